// Round 1
// baseline (487.301 us; speedup 1.0000x reference)
//
#include <hip/hip_runtime.h>
#include <stdint.h>

// Periodic radius-graph neighbor list (AlphaNet).
// B=16 images, N=256 atoms, C=27 periodic images, M=N*C=6912 candidates/receiver.
// Outputs (flat concat, all written as float32):
//   dist [B,N,M], dvec [B,N,M,3], num_neighbors_image [B]
// keep rule: within = (dsqr<=25 && dsqr>1e-4); stable-sort rank among receiver's
// candidates < 32. Stable sort == lexicographic key (f32bits(dsqr), m); kept iff
// key <= tau where tau = 32nd-smallest within-key (or MAX if K<32).

constexpr int B_ = 16, N_ = 256, C_ = 27;
constexpr int M_ = N_ * C_;          // 6912
constexpr int G_ = M_ / 4;           // 1728 float4 groups per receiver
constexpr int MAXC = 1024;           // LDS candidate slots (mean ~78, huge margin)
constexpr int KMAX = 32;

__global__ __launch_bounds__(256)
void nbr_kernel(const float* __restrict__ pos,    // [B,N,3]
                const float* __restrict__ cell,   // [B,3,3]
                float* __restrict__ dist,         // [B,N,M]
                float* __restrict__ dvec,         // [B,N,M,3]
                float* __restrict__ nn)           // [B] (float counts)
{
#pragma clang fp contract(off)
    __shared__ float ps[N_ * 3];
    __shared__ float offs[C_ * 3];
    __shared__ unsigned long long keys[MAXC];
    __shared__ int cnt;
    __shared__ unsigned long long tau_s;

    const int bi  = blockIdx.x;        // b*N + i
    const int b   = bi >> 8;
    const int i   = bi & 255;
    const int tid = threadIdx.x;

    // stage pos[b] and the 27 lattice offsets
    const float* pb = pos + b * N_ * 3;
    for (int t = tid; t < N_ * 3; t += 256) ps[t] = pb[t];
    if (tid < C_) {
        const float n1 = (float)(tid / 9 - 1);
        const float n2 = (float)((tid / 3) % 3 - 1);
        const float n3 = (float)(tid % 3 - 1);
        const float* cb = cell + b * 9;
        for (int d = 0; d < 3; ++d)
            offs[tid * 3 + d] = n1 * cb[d] + n2 * cb[3 + d] + n3 * cb[6 + d];
    }
    if (tid == 0) { cnt = 0; tau_s = ~0ULL; }
    __syncthreads();

    const float pix = ps[i * 3 + 0], piy = ps[i * 3 + 1], piz = ps[i * 3 + 2];

    // pass 1: collect within-radius candidate keys
    for (int k = 0; k < C_; ++k) {
        const int m = tid + (k << 8);          // covers 0..6911 exactly
        const int j = m / C_;
        const int c = m - j * C_;
        const float sx = ps[j * 3 + 0] + offs[c * 3 + 0];
        const float sy = ps[j * 3 + 1] + offs[c * 3 + 1];
        const float sz = ps[j * 3 + 2] + offs[c * 3 + 2];
        const float dx = pix - sx, dy = piy - sy, dz = piz - sz;
        const float dsq = dx * dx + dy * dy + dz * dz;
        if (dsq <= 25.0f && dsq > 1e-4f) {
            const int idx = atomicAdd(&cnt, 1);
            if (idx < MAXC)
                keys[idx] = ((unsigned long long)__float_as_uint(dsq) << 32) | (unsigned)m;
        }
    }
    __syncthreads();

    // rank scan: find tau = key with rank 31 (unique keys -> unique writer)
    int K = cnt; if (K > MAXC) K = MAXC;
    for (int idx = tid; idx < K; idx += 256) {
        const unsigned long long key = keys[idx];
        int r = 0;
        for (int q = 0; q < K; ++q) r += (keys[q] < key) ? 1 : 0;
        if (r == KMAX - 1) tau_s = key;
    }
    __syncthreads();

    if (tid == 0)
        atomicAdd(&nn[b], (float)(K < KMAX ? K : KMAX)); // exact for small ints

    const unsigned long long tau = tau_s;
    float* __restrict__ drow = dist + (size_t)bi * M_;
    float* __restrict__ vrow = dvec + (size_t)bi * (size_t)(M_ * 3);

    // pass 2: write every candidate (zeros included) with aligned float4 stores
    for (int g = tid; g < G_; g += 256) {
        const int m0 = g * 4;
        float dv[4], vv[12];
        #pragma unroll
        for (int u = 0; u < 4; ++u) {
            const int m = m0 + u;
            const int j = m / C_;
            const int c = m - j * C_;
            const float sx = ps[j * 3 + 0] + offs[c * 3 + 0];
            const float sy = ps[j * 3 + 1] + offs[c * 3 + 1];
            const float sz = ps[j * 3 + 2] + offs[c * 3 + 2];
            const float dx = pix - sx, dy = piy - sy, dz = piz - sz;
            const float dsq = dx * dx + dy * dy + dz * dz;
            const bool within = (dsq <= 25.0f) && (dsq > 1e-4f);
            const unsigned long long key =
                ((unsigned long long)__float_as_uint(dsq) << 32) | (unsigned)m;
            const bool keep = within && (key <= tau);
            dv[u]         = keep ? sqrtf(dsq) : 0.0f;
            vv[u * 3 + 0] = keep ? dx : 0.0f;
            vv[u * 3 + 1] = keep ? dy : 0.0f;
            vv[u * 3 + 2] = keep ? dz : 0.0f;
        }
        *(float4*)(drow + m0) = make_float4(dv[0], dv[1], dv[2], dv[3]);
        float4* vp = (float4*)(vrow + (size_t)m0 * 3);
        vp[0] = make_float4(vv[0], vv[1], vv[2],  vv[3]);
        vp[1] = make_float4(vv[4], vv[5], vv[6],  vv[7]);
        vp[2] = make_float4(vv[8], vv[9], vv[10], vv[11]);
    }
}

extern "C" void kernel_launch(void* const* d_in, const int* in_sizes, int n_in,
                              void* d_out, int out_size, void* d_ws, size_t ws_size,
                              hipStream_t stream)
{
    const float* pos  = (const float*)d_in[0];
    const float* cell = (const float*)d_in[1];
    float* dist = (float*)d_out;
    float* dvec = dist + (size_t)B_ * N_ * M_;
    float* nn   = dvec + (size_t)B_ * N_ * M_ * 3;
    hipMemsetAsync(nn, 0, B_ * sizeof(float), stream);   // zero count tail
    nbr_kernel<<<dim3(B_ * N_), dim3(256), 0, stream>>>(pos, cell, dist, dvec, nn);
}

// Round 2
// 472.312 us; speedup vs baseline: 1.0317x; 1.0317x over previous
//
#include <hip/hip_runtime.h>
#include <stdint.h>

// Periodic radius-graph neighbor list (AlphaNet). B=16, N=256, C=27, M=6912.
// Outputs (flat f32 concat): dist [B,N,M], dvec [B,N,M,3], num_neighbors_image [B].
// keep = within-radius (1e-4 < dsqr <= 25) AND stable-sort rank < 32.
// Strategy: per-receiver block. Pass 1 collects the ~78 within-radius candidates
// (bit-exact numpy arithmetic) into LDS. Output is zero-filled with pure float4
// stores (no per-candidate compute), then the <=32 kept edges are scattered from
// the LDS-cached values. Write-BW-bound: 453 MB of stores.

constexpr int B_ = 16, N_ = 256, C_ = 27;
constexpr int M_ = N_ * C_;      // 6912
constexpr int MAXC = 256;        // candidate slots; mean ~78, max ~110 (uniform box)
constexpr int KMAX = 32;

__global__ __launch_bounds__(256)
void nbr_kernel(const float* __restrict__ pos,    // [B,N,3]
                const float* __restrict__ cell,   // [B,3,3]
                float* __restrict__ dist,         // [B,N,M]
                float* __restrict__ dvec,         // [B,N,M,3]
                float* __restrict__ nn)           // [B] (float counts)
{
#pragma clang fp contract(off)
    __shared__ float offx[C_], offy[C_], offz[C_];
    __shared__ unsigned long long keys[MAXC];
    __shared__ float4 vals[MAXC];               // dx,dy,dz,dsq
    __shared__ int cnt;

    const int bi  = blockIdx.x;   // b*N + i
    const int b   = bi >> 8;
    const int i   = bi & 255;
    const int tid = threadIdx.x;

    const float* pb = pos + b * N_ * 3;
    // this thread's source atom j = tid (coalesced-ish, L1-resident: 3 KB/image)
    const float pjx = pb[tid * 3 + 0], pjy = pb[tid * 3 + 1], pjz = pb[tid * 3 + 2];
    // receiver atom (wave-uniform -> scalar loads)
    const float pix = pb[i * 3 + 0], piy = pb[i * 3 + 1], piz = pb[i * 3 + 2];

    if (tid < C_) {
        const float n1 = (float)(tid / 9 - 1);
        const float n2 = (float)((tid / 3) % 3 - 1);
        const float n3 = (float)(tid % 3 - 1);
        const float* cb = cell + b * 9;
        offx[tid] = n1 * cb[0] + n2 * cb[3] + n3 * cb[6];
        offy[tid] = n1 * cb[1] + n2 * cb[4] + n3 * cb[7];
        offz[tid] = n1 * cb[2] + n2 * cb[5] + n3 * cb[8];
    }
    if (tid == 0) cnt = 0;
    __syncthreads();

    float* __restrict__ drow = dist + (size_t)bi * M_;
    float* __restrict__ vrow = dvec + (size_t)bi * (size_t)(M_ * 3);

    // zero-fill this receiver's rows: 6912 float4 stores per block, fully coalesced.
    // Issued first so the stores drain while pass-1 VALU work proceeds.
    {
        const float4 z = make_float4(0.f, 0.f, 0.f, 0.f);
        float4* dp = (float4*)drow;               // 1728 groups
        float4* vp = (float4*)vrow;               // 5184 groups
        for (int t = tid; t < M_ / 4; t += 256) dp[t] = z;
        for (int t = tid; t < 3 * M_ / 4; t += 256) vp[t] = z;
    }

    // pass 1: source j = tid, loop 27 periodic images (offs reads broadcast).
    // Arithmetic order matches numpy exactly: s = pj + off; d = pi - s;
    // dsq = ((dx*dx + dy*dy) + dz*dz), contract off -> bit-exact keep set.
    #pragma unroll 1
    for (int c = 0; c < C_; ++c) {
        const float sx = pjx + offx[c], sy = pjy + offy[c], sz = pjz + offz[c];
        const float dx = pix - sx, dy = piy - sy, dz = piz - sz;
        const float dsq = dx * dx + dy * dy + dz * dz;
        if (dsq <= 25.0f && dsq > 1e-4f) {
            const int idx = atomicAdd(&cnt, 1);
            if (idx < MAXC) {
                keys[idx] = ((unsigned long long)__float_as_uint(dsq) << 32)
                          | (unsigned)(tid * C_ + c);
                vals[idx] = make_float4(dx, dy, dz, dsq);
            }
        }
    }
    __syncthreads();   // keys/vals complete; also orders fill stores before scatter

    int K = cnt; if (K > MAXC) K = MAXC;
    if (tid == 0)
        atomicAdd(&nn[b], (float)(K < KMAX ? K : KMAX));  // exact for small ints

    // rank scan (stable: key = (f32bits(dsq), m), unique) + scatter kept edges
    for (int idx = tid; idx < K; idx += 256) {
        const unsigned long long key = keys[idx];
        int r = 0;
        for (int q = 0; q < K; ++q) r += (keys[q] < key) ? 1 : 0;
        if (r < KMAX) {
            const int m = (int)(key & 0xffffffffu);
            const float4 v = vals[idx];
            drow[m]         = sqrtf(v.w);
            vrow[m * 3 + 0] = v.x;
            vrow[m * 3 + 1] = v.y;
            vrow[m * 3 + 2] = v.z;
        }
    }
}

extern "C" void kernel_launch(void* const* d_in, const int* in_sizes, int n_in,
                              void* d_out, int out_size, void* d_ws, size_t ws_size,
                              hipStream_t stream)
{
    const float* pos  = (const float*)d_in[0];
    const float* cell = (const float*)d_in[1];
    float* dist = (float*)d_out;
    float* dvec = dist + (size_t)B_ * N_ * M_;
    float* nn   = dvec + (size_t)B_ * N_ * M_ * 3;
    hipMemsetAsync(nn, 0, B_ * sizeof(float), stream);   // zero count tail
    nbr_kernel<<<dim3(B_ * N_), dim3(256), 0, stream>>>(pos, cell, dist, dvec, nn);
}